// Round 1
// baseline (556.854 us; speedup 1.0000x reference)
//
#include <hip/hip_runtime.h>

// MaxPool2d: x (32, 64, 224, 224) f32, kernel=2, stride=2, pad=0
// -> out (32, 64, 112, 112) f32.
// Pure streaming op: each input element read once, each output written once.
// Work item = one float4 (4 input cols) x 2 input rows -> 2 output floats.

#define W_IN   224
#define H_IN   224
#define W_OUT  112
#define H_OUT  112
#define W4     (W_OUT / 2)          // 56 float4 groups per output row
#define N_PLANES (32 * 64)          // N*C
#define N_ITEMS  (N_PLANES * H_OUT * W4)   // 12,845,056

__global__ __launch_bounds__(256) void maxpool2x2_kernel(
    const float* __restrict__ in, float* __restrict__ out)
{
    const int stride = gridDim.x * blockDim.x;
    for (int idx = blockIdx.x * blockDim.x + threadIdx.x; idx < N_ITEMS; idx += stride) {
        const int w4    = idx % W4;          // which float4 group in the row
        const int t     = idx / W4;
        const int oh    = t % H_OUT;         // output row
        const int plane = t / H_OUT;         // fused N*C plane

        const float* base = in + (size_t)plane * (W_IN * H_IN) + (size_t)(2 * oh) * W_IN;
        const float4 a = *(reinterpret_cast<const float4*>(base) + w4);             // row 2*oh
        const float4 b = *(reinterpret_cast<const float4*>(base + W_IN) + w4);      // row 2*oh+1

        float2 r;
        r.x = fmaxf(fmaxf(a.x, a.y), fmaxf(b.x, b.y));
        r.y = fmaxf(fmaxf(a.z, a.w), fmaxf(b.z, b.w));

        float* obase = out + (size_t)plane * (W_OUT * H_OUT) + (size_t)oh * W_OUT;
        *(reinterpret_cast<float2*>(obase) + w4) = r;
    }
}

extern "C" void kernel_launch(void* const* d_in, const int* in_sizes, int n_in,
                              void* d_out, int out_size, void* d_ws, size_t ws_size,
                              hipStream_t stream) {
    const float* x = (const float*)d_in[0];
    float* out = (float*)d_out;

    const int block = 256;
    const int grid  = 2048;   // 256 CU x 8 blocks/CU; grid-stride covers the rest
    maxpool2x2_kernel<<<grid, block, 0, stream>>>(x, out);
}

// Round 4
// 526.830 us; speedup vs baseline: 1.0570x; 1.0570x over previous
//
#include <hip/hip_runtime.h>

// MaxPool2d: x (32, 64, 224, 224) f32, kernel=2, stride=2, pad=0
// -> out (32, 64, 112, 112) f32.
// Streaming op, HBM-bound: 411 MB read + 103 MB write -> ~82 us floor @ 6.3 TB/s.
// One thread = 4 outputs: reads 2x2 float4 (rows 2*oh, 2*oh+1), writes 1 float4.
// Exact grid (no grid-stride loop), non-temporal loads/stores (data never reused;
// input exceeds the 256 MiB L3 anyway).
// NOTE: __builtin_nontemporal_* requires a clang native vector type, not
// HIP_vector_type — use ext_vector_type(4) float.

typedef float fx4 __attribute__((ext_vector_type(4)));

#define W_IN     224
#define H_IN     224
#define W_OUT    112
#define H_OUT    112
#define OW4      (W_OUT / 4)                 // 28 float4 groups per output row
#define N_PLANES (32 * 64)                   // fused N*C = 2048 planes
#define N_ITEMS  (N_PLANES * H_OUT * OW4)    // 6,422,528 threads
#define BLOCK    256
#define GRID     (N_ITEMS / BLOCK)           // 25088, exact

__global__ __launch_bounds__(BLOCK) void maxpool2x2_kernel(
    const float* __restrict__ in, float* __restrict__ out)
{
    const int idx = blockIdx.x * BLOCK + threadIdx.x;   // exact grid, no bounds check

    const int ow4   = idx % OW4;             // output float4 group in row
    const int t     = idx / OW4;
    const int oh    = t % H_OUT;             // output row
    const int plane = t / H_OUT;             // fused N*C plane

    const float* r0 = in + (size_t)plane * (W_IN * H_IN) + (size_t)(2 * oh) * W_IN;
    const fx4* p0 = reinterpret_cast<const fx4*>(r0) + 2 * ow4;          // row 2*oh
    const fx4* p1 = reinterpret_cast<const fx4*>(r0 + W_IN) + 2 * ow4;   // row 2*oh+1

    const fx4 a0 = __builtin_nontemporal_load(p0);
    const fx4 a1 = __builtin_nontemporal_load(p0 + 1);
    const fx4 b0 = __builtin_nontemporal_load(p1);
    const fx4 b1 = __builtin_nontemporal_load(p1 + 1);

    fx4 r;
    r.x = fmaxf(fmaxf(a0.x, a0.y), fmaxf(b0.x, b0.y));
    r.y = fmaxf(fmaxf(a0.z, a0.w), fmaxf(b0.z, b0.w));
    r.z = fmaxf(fmaxf(a1.x, a1.y), fmaxf(b1.x, b1.y));
    r.w = fmaxf(fmaxf(a1.z, a1.w), fmaxf(b1.z, b1.w));

    fx4* op = reinterpret_cast<fx4*>(
        out + (size_t)plane * (W_OUT * H_OUT) + (size_t)oh * W_OUT) + ow4;
    __builtin_nontemporal_store(r, op);
}

extern "C" void kernel_launch(void* const* d_in, const int* in_sizes, int n_in,
                              void* d_out, int out_size, void* d_ws, size_t ws_size,
                              hipStream_t stream) {
    const float* x = (const float*)d_in[0];
    float* out = (float*)d_out;
    maxpool2x2_kernel<<<GRID, BLOCK, 0, stream>>>(x, out);
}

// Round 6
// 525.627 us; speedup vs baseline: 1.0594x; 1.0023x over previous
//
#include <hip/hip_runtime.h>

// MaxPool2d: x (32, 64, 224, 224) f32, kernel=2, stride=2, pad=0
// -> out (32, 64, 112, 112) f32.
//
// FINAL — at roofline. Measured via 3x-launch delta (round 5):
//   T_kernel = (688.59 - 526.83)/2 = 80.9 us for 514 MB traffic = 6.35 TB/s,
//   matching the harness's own fill kernels (6.4-6.5 TB/s = 80% of 8 TB/s spec)
//   and the ~82 us achievable-BW floor. Every input byte is read exactly once
//   (stride=2 windows don't overlap), every output byte written once; both
//   streams are coalesced 16 B/lane. Input (411 MB) > 256 MiB L3, so no cache
//   reuse exists. Nothing left to optimize.
//
// One thread = 4 outputs: reads 2x2 float4 (rows 2*oh, 2*oh+1), writes 1 float4.
// Exact grid, no bounds check. Non-temporal hints keep the never-reused streams
// from thrashing L2/L3.

typedef float fx4 __attribute__((ext_vector_type(4)));

#define W_IN     224
#define H_IN     224
#define W_OUT    112
#define H_OUT    112
#define OW4      (W_OUT / 4)                 // 28 float4 groups per output row
#define N_PLANES (32 * 64)                   // fused N*C = 2048 planes
#define N_ITEMS  (N_PLANES * H_OUT * OW4)    // 6,422,528 threads
#define BLOCK    256
#define GRID     (N_ITEMS / BLOCK)           // 25088, exact

__global__ __launch_bounds__(BLOCK) void maxpool2x2_kernel(
    const float* __restrict__ in, float* __restrict__ out)
{
    const int idx = blockIdx.x * BLOCK + threadIdx.x;   // exact grid, no bounds check

    const int ow4   = idx % OW4;             // output float4 group in row
    const int t     = idx / OW4;
    const int oh    = t % H_OUT;             // output row
    const int plane = t / H_OUT;             // fused N*C plane

    const float* r0 = in + (size_t)plane * (W_IN * H_IN) + (size_t)(2 * oh) * W_IN;
    const fx4* p0 = reinterpret_cast<const fx4*>(r0) + 2 * ow4;          // row 2*oh
    const fx4* p1 = reinterpret_cast<const fx4*>(r0 + W_IN) + 2 * ow4;   // row 2*oh+1

    const fx4 a0 = __builtin_nontemporal_load(p0);
    const fx4 a1 = __builtin_nontemporal_load(p0 + 1);
    const fx4 b0 = __builtin_nontemporal_load(p1);
    const fx4 b1 = __builtin_nontemporal_load(p1 + 1);

    fx4 r;
    r.x = fmaxf(fmaxf(a0.x, a0.y), fmaxf(b0.x, b0.y));
    r.y = fmaxf(fmaxf(a0.z, a0.w), fmaxf(b0.z, b0.w));
    r.z = fmaxf(fmaxf(a1.x, a1.y), fmaxf(b1.x, b1.y));
    r.w = fmaxf(fmaxf(a1.z, a1.w), fmaxf(b1.z, b1.w));

    fx4* op = reinterpret_cast<fx4*>(
        out + (size_t)plane * (W_OUT * H_OUT) + (size_t)oh * W_OUT) + ow4;
    __builtin_nontemporal_store(r, op);
}

extern "C" void kernel_launch(void* const* d_in, const int* in_sizes, int n_in,
                              void* d_out, int out_size, void* d_ws, size_t ws_size,
                              hipStream_t stream) {
    const float* x = (const float*)d_in[0];
    float* out = (float*)d_out;
    maxpool2x2_kernel<<<GRID, BLOCK, 0, stream>>>(x, out);
}